// Round 15
// baseline (41.814 us; speedup 1.0000x reference)
//
#include <hip/hip_runtime.h>
#include <hip/hip_bf16.h>
#include <stdint.h>

// LS2T order-4 iterated sums. B=32,T=2048,F=128,m=64,C=10.
// R15 = R14 with the X LDS tile removed -> ZERO-BARRIER main kernel.
//  - af built per-wave directly from global X (all 4 waves need identical af;
//    4x reads hit L2). R11 proved this load pattern correct.
//  - W stays DMA'd global->LDS; each wave's quarter is private (nt*4096),
//    so with xs gone NO __syncthreads is needed at all.
//  - LDS 48->32KB: 4 blocks/CU -> 1024-block grid = ONE batch, no tail;
//    16 decoupled waves/CU overlap DMA/MFMA/VALU statistically.
//  - VMCNT(0) after prologue re-anchors the counted schedule (was done by
//    syncthreads' implicit drain in R14). P0-P9 pipeline verbatim R14.

typedef __attribute__((ext_vector_type(8))) short short8;
typedef __attribute__((ext_vector_type(4))) float f32x4;

#define T_ 2048
#define F_ 128
#define M_ 64
#define NTILE 40
#define SEGS 32

#define VMCNT(n) asm volatile("s_waitcnt vmcnt(" #n ")" ::: "memory")

__device__ __forceinline__ unsigned short f2bf(float x){
  unsigned int u = __float_as_uint(x);
  u += 0x7FFFu + ((u>>16)&1u);       // RNE
  return (unsigned short)(u>>16);
}
__device__ __forceinline__ unsigned pk2(float lo, float hi){
  return (unsigned)f2bf(lo) | ((unsigned)f2bf(hi)<<16);
}

__device__ __forceinline__ void gl_lds16(const char* g, char* s){
  __builtin_amdgcn_global_load_lds(
    (const __attribute__((address_space(1))) unsigned int*)g,
    (__attribute__((address_space(3))) unsigned int*)s, 16, 0, 0);
}

// ---- Kernel 1: W fp32 -> bf16 MFMA B-fragments ----
__global__ __launch_bounds__(256) void prep_w_k(const float* __restrict__ Wk,
                                                uint4* __restrict__ wsw){
  int g = blockIdx.x*256 + threadIdx.x;
  if (g >= NTILE*4*64) return;
  int l  = g & 63;
  int kk = (g >> 6) & 3;
  int n  = g >> 8;
  int cm = n*16 + (l & 15);
  int c  = cm >> 6, mm = cm & 63;
  int kb = kk*32 + (l>>4)*8;
  unsigned short v[8];
  #pragma unroll
  for (int j=0;j<8;++j) v[j] = f2bf(Wk[((c*F_) + kb + j)*M_ + mm]);
  uint4 o;
  o.x = (unsigned)v[0] | ((unsigned)v[1]<<16);
  o.y = (unsigned)v[2] | ((unsigned)v[3]<<16);
  o.z = (unsigned)v[4] | ((unsigned)v[5]<<16);
  o.w = (unsigned)v[6] | ((unsigned)v[7]<<16);
  wsw[g] = o;
}

__device__ __forceinline__ float sx(float v, int mk){ return __shfl_xor(v, mk, 64); }

// ---- Kernel 2: fused GEMM + in-register scan, 10-phase W pipeline ----
// grid (seg=32, b=32), 256 thr = 4 waves, wave = nt (16-m slice), 64 t/wave.
__global__ __launch_bounds__(256) void ls2t_main_k(const float* __restrict__ X,
                                                   const float* __restrict__ bias,
                                                   const char* __restrict__ wsrc,
                                                   float* __restrict__ agg){
  const int seg = blockIdx.x;
  const int b   = blockIdx.y;
  const int tid = threadIdx.x;
  const int nt  = tid >> 6;
  const int l   = tid & 63;
  const int lr  = l & 15, lg = l >> 4;
  const int t0  = seg*64;
  const int mcol = nt*16 + lr;

  __shared__ __align__(16) char wbuf[32768];   // 2 x 16KB W comp buffers

  // Stage comp c's fragments for THIS wave's quarter into buf (DMA, no VGPR).
  auto stageC = [&](int c, int buf){
    const char* s = wsrc + c*16384 + nt*4096 + l*16;
    char* d = wbuf + buf*16384 + nt*4096 + l*16;
    #pragma unroll
    for (int i=0;i<4;++i) gl_lds16(s + i*1024, d + i*1024);
  };

  // Prefetch c0,c1 (drained by the explicit VMCNT(0) below).
  stageC(0,0); stageC(1,1);

  // Hoisted bias.
  float bz[10];
  #pragma unroll
  for (int c=0;c<10;++c) bz[c] = bias[c*M_ + mcol];

  // A-fragments direct from global (identical for all 4 waves; L2 absorbs):
  // af[s][kk] = X[t0 + lr*4 + s][kk*32 + lg*8 .. +8] as bf16.
  short8 af[4][4];
  #pragma unroll
  for (int s=0;s<4;++s){
    const float* xr = X + ((size_t)b*T_ + t0 + lr*4 + s)*F_ + lg*8;
    #pragma unroll
    for (int kk=0;kk<4;++kk){
      float4 v0 = *reinterpret_cast<const float4*>(xr + kk*32);
      float4 v1 = *reinterpret_cast<const float4*>(xr + kk*32 + 4);
      uint4 q;
      q.x = pk2(v0.x, v0.y);
      q.y = pk2(v0.z, v0.w);
      q.z = pk2(v1.x, v1.y);
      q.w = pk2(v1.z, v1.w);
      af[s][kk] = reinterpret_cast<short8&>(q);
    }
  }

  // Re-anchor the counted-vmcnt schedule: drain af + bias + c0/c1 DMA.
  VMCNT(0);

  // MFMA c from buf into A[4] using register-resident af.
  auto computeC = [&](f32x4 (&A)[4], int buf){
    const char* wb = wbuf + buf*16384 + nt*4096;
    #pragma unroll
    for (int s=0;s<4;++s) A[s] = (f32x4){0.f,0.f,0.f,0.f};
    #pragma unroll
    for (int kk=0;kk<4;++kk){
      short8 wf = *reinterpret_cast<const short8*>(wb + kk*1024 + l*16);
      #pragma unroll
      for (int s=0;s<4;++s)
        A[s] = __builtin_amdgcn_mfma_f32_16x16x32_bf16(af[s][kk], wf, A[s], 0,0,0);
    }
  };

  float* ob = agg + (((size_t)b*SEGS + seg)*20)*64 + mcol;
  f32x4 A0[4], A1[4], A2[4], A3[4];

  // ---- P0: c0 (b0) -> level 1 scan; stage c2->b0 ----
  computeC(A0,0);
  stageC(2,0);
  {
    float S0 = 0.f;
    #pragma unroll
    for (int j=0;j<4;++j)
      #pragma unroll
      for (int s=0;s<4;++s) S0 += A0[s][j] + bz[0];
    #pragma unroll
    for (int st=0; st<2; ++st) S0 += sx(S0, 16<<st);
    if (lg==0) ob[0*64] = S0;
  }
  // ---- P1: c1 (b1) -> A0; stage c3->b1 ----
  computeC(A0,1);
  stageC(3,1);
  // ---- P2: c2 (b0) -> A1; stage c4->b0; level 2 scan ----
  VMCNT(4);
  computeC(A1,0);
  stageC(4,0);
  {
    float S1=0.f,S2=0.f,I21=0.f;
    #pragma unroll
    for (int j=0;j<4;++j)
      #pragma unroll
      for (int s=0;s<4;++s){
        float a1 = A0[s][j] + bz[1];
        float a2 = A1[s][j] + bz[2];
        I21 += a2*S1; S1 += a1; S2 += a2;
      }
    #pragma unroll
    for (int st=0; st<2; ++st){
      int mk = 16<<st; bool up = (l & mk)!=0;
      float o1=sx(S1,mk), o2=sx(S2,mk), oI=sx(I21,mk);
      float B1=up?o1:S1, B2=up?o2:S2, BI=up?oI:I21;
      float C1=up?S1:o1, C2=up?S2:o2, CI=up?I21:oI;
      S1=B1+C1; S2=B2+C2; I21=BI+CI + B1*C2;
    }
    if (lg==0) ob[1*64]=S1; else if (lg==1) ob[2*64]=S2; else if (lg==2) ob[10*64]=I21;
  }
  // ---- P3: c3 (b1) -> A0; stage c5->b1 ----
  VMCNT(4);
  computeC(A0,1);
  stageC(5,1);
  // ---- P4: c4 (b0) -> A1; stage c6->b0 ----
  VMCNT(4);
  computeC(A1,0);
  stageC(6,0);
  // ---- P5: c5 (b1) -> A2; stage c7->b1; level 3 scan ----
  VMCNT(4);
  computeC(A2,1);
  stageC(7,1);
  {
    float S3=0.f,S4=0.f,S5=0.f,I43=0.f,I54=0.f,I543=0.f;
    #pragma unroll
    for (int j=0;j<4;++j)
      #pragma unroll
      for (int s=0;s<4;++s){
        float a3 = A0[s][j] + bz[3];
        float a4 = A1[s][j] + bz[4];
        float a5 = A2[s][j] + bz[5];
        I543 += a5*I43; I54 += a5*S4; I43 += a4*S3;
        S3 += a3; S4 += a4; S5 += a5;
      }
    #pragma unroll
    for (int st=0; st<2; ++st){
      int mk = 16<<st; bool up = (l & mk)!=0;
      float o3=sx(S3,mk), o4=sx(S4,mk), o5=sx(S5,mk);
      float oA=sx(I43,mk), oB=sx(I54,mk), oC=sx(I543,mk);
      float B3=up?o3:S3, B4=up?o4:S4, B5=up?o5:S5;
      float BA=up?oA:I43, BB=up?oB:I54, BC_=up?oC:I543;
      float C3=up?S3:o3, C4=up?S4:o4, C5=up?S5:o5;
      float CA=up?I43:oA, CB=up?I54:oB, CC=up?I543:oC;
      float n43 = BA+CA + B3*C4;
      float n54 = BB+CB + B4*C5;
      float n543= BC_+CC + BA*C5 + B3*CB;
      S3=B3+C3; S4=B4+C4; S5=B5+C5; I43=n43; I54=n54; I543=n543;
    }
    if      (lg==0){ ob[3*64]=S3;  ob[11*64]=I43; }
    else if (lg==1){ ob[4*64]=S4;  ob[12*64]=I54; }
    else if (lg==2){ ob[5*64]=S5;  ob[13*64]=I543; }
  }
  // ---- P6: c6 (b0) -> A0; stage c8->b0 ----
  VMCNT(4);
  computeC(A0,0);
  stageC(8,0);
  // ---- P7: c7 (b1) -> A1; stage c9->b1 ----
  VMCNT(4);
  computeC(A1,1);
  stageC(9,1);
  // ---- P8: c8 (b0) -> A2 ----
  VMCNT(4);
  computeC(A2,0);
  // ---- P9: c9 (b1) -> A3; level 4 scan ----
  VMCNT(0);
  computeC(A3,1);
  {
    float S6=0.f,S7=0.f,S8=0.f,S9=0.f;
    float I76=0.f,I87=0.f,I98=0.f,I876=0.f,I987=0.f,I9876=0.f;
    #pragma unroll
    for (int j=0;j<4;++j)
      #pragma unroll
      for (int s=0;s<4;++s){
        float a6 = A0[s][j] + bz[6];
        float a7 = A1[s][j] + bz[7];
        float a8 = A2[s][j] + bz[8];
        float a9 = A3[s][j] + bz[9];
        I9876 += a9*I876; I987 += a9*I87; I98 += a9*S8;
        I876  += a8*I76;  I87  += a8*S7;
        I76   += a7*S6;
        S6 += a6; S7 += a7; S8 += a8; S9 += a9;
      }
    #pragma unroll
    for (int st=0; st<2; ++st){
      int mk = 16<<st; bool up = (l & mk)!=0;
      float o6=sx(S6,mk), o7=sx(S7,mk), o8=sx(S8,mk), o9=sx(S9,mk);
      float oA=sx(I76,mk), oB=sx(I87,mk), oC=sx(I98,mk);
      float oD=sx(I876,mk), oE=sx(I987,mk), oF=sx(I9876,mk);
      float B6=up?o6:S6, B7=up?o7:S7, B8=up?o8:S8, B9=up?o9:S9;
      float BA=up?oA:I76, BB=up?oB:I87, BC_=up?oC:I98;
      float BD=up?oD:I876, BE=up?oE:I987, BF=up?oF:I9876;
      float C6=up?S6:o6, C7=up?S7:o7, C8=up?S8:o8, C9=up?S9:o9;
      float CA=up?I76:oA, CB=up?I87:oB, CC=up?I98:oC;
      float CD=up?I876:oD, CE=up?I987:oE, CF=up?I9876:oF;
      float n76  = BA+CA + B6*C7;
      float n87  = BB+CB + B7*C8;
      float n98  = BC_+CC + B8*C9;
      float n876 = BD+CD + BA*C8 + B6*CB;
      float n987 = BE+CE + BB*C9 + B7*CC;
      float n9876= BF+CF + BD*C9 + BA*CC + B6*CE;
      S6=B6+C6; S7=B7+C7; S8=B8+C8; S9=B9+C9;
      I76=n76; I87=n87; I98=n98; I876=n876; I987=n987; I9876=n9876;
    }
    if      (lg==0){ ob[6*64]=S6; ob[14*64]=I76; ob[18*64]=I987; }
    else if (lg==1){ ob[7*64]=S7; ob[15*64]=I87; ob[19*64]=I9876; }
    else if (lg==2){ ob[8*64]=S8; ob[16*64]=I98; }
    else           { ob[9*64]=S9; ob[17*64]=I876; }
  }
}

// state layout: [0..9]=S0..S9, [10]=I21,[11]=I43,[12]=I54,[13]=I543,
// [14]=I76,[15]=I87,[16]=I98,[17]=I876,[18]=I987,[19]=I9876
__device__ __forceinline__ void compose(float* A, const float* Bv){
  float n10 = A[10]+Bv[10] + A[1]*Bv[2];
  float n11 = A[11]+Bv[11] + A[3]*Bv[4];
  float n12 = A[12]+Bv[12] + A[4]*Bv[5];
  float n13 = A[13]+Bv[13] + A[11]*Bv[5] + A[3]*Bv[12];
  float n14 = A[14]+Bv[14] + A[6]*Bv[7];
  float n15 = A[15]+Bv[15] + A[7]*Bv[8];
  float n16 = A[16]+Bv[16] + A[8]*Bv[9];
  float n17 = A[17]+Bv[17] + A[14]*Bv[8] + A[6]*Bv[15];
  float n18 = A[18]+Bv[18] + A[15]*Bv[9] + A[7]*Bv[16];
  float n19 = A[19]+Bv[19] + A[17]*Bv[9] + A[14]*Bv[16] + A[6]*Bv[18];
  #pragma unroll
  for (int c=0;c<10;++c) A[c] += Bv[c];
  A[10]=n10; A[11]=n11; A[12]=n12; A[13]=n13; A[14]=n14;
  A[15]=n15; A[16]=n16; A[17]=n17; A[18]=n18; A[19]=n19;
}

// ---- Kernel 3: fold 32 segments per (b,m); 8-way parallel + LDS tree ----
__global__ __launch_bounds__(512) void combine_k(const float* __restrict__ agg,
                                                 float* __restrict__ out){
  int b  = blockIdx.x;            // 32 blocks
  int m  = threadIdx.x & 63;
  int sg = threadIdx.x >> 6;      // 0..7, folds segs [sg*4, sg*4+4)
  const float* base = agg + ((size_t)b*SEGS*20)*64 + m;
  float st[20];
  #pragma unroll
  for (int i=0;i<20;++i) st[i]=0.f;
  for (int s=sg*4; s<sg*4+4; ++s){
    const float* a = base + (size_t)s*20*64;
    float Bv[20];
    #pragma unroll
    for (int i=0;i<20;++i) Bv[i] = a[i*64];
    compose(st, Bv);
  }
  __shared__ float buf[8][20][64];   // 40KB
  #pragma unroll
  for (int i=0;i<20;++i) buf[sg][i][m] = st[i];
  __syncthreads();
  if (sg==0){
    #pragma unroll
    for (int g=1; g<8; ++g){
      float Bv[20];
      #pragma unroll
      for (int i=0;i<20;++i) Bv[i] = buf[g][i][m];
      compose(st, Bv);
    }
    out[(b*4+0)*64+m] = st[0];    // y1 = S0 total
    out[(b*4+1)*64+m] = st[10];   // y2 = I21 total
    out[(b*4+2)*64+m] = st[13];   // y3 = I543 total
    out[(b*4+3)*64+m] = st[19];   // y4 = I9876 total
  }
}

extern "C" void kernel_launch(void* const* d_in, const int* in_sizes, int n_in,
                              void* d_out, int out_size, void* d_ws, size_t ws_size,
                              hipStream_t stream){
  const float* X    = (const float*)d_in[0];   // [32,2048,128]
  const float* Wk   = (const float*)d_in[1];   // [10,128,64]
  const float* bias = (const float*)d_in[2];   // [10,64]
  float* out = (float*)d_out;                  // [32,4,64]

  uint4* wsw = (uint4*)d_ws;                                 // 160 KB W frags
  float* agg = (float*)((char*)d_ws + (1u<<20));             // 5.25 MB aggregates

  hipLaunchKernelGGL(prep_w_k,    dim3(40),     dim3(256), 0, stream, Wk, wsw);
  hipLaunchKernelGGL(ls2t_main_k, dim3(32,32),  dim3(256), 0, stream,
                     X, bias, (const char*)d_ws, agg);
  hipLaunchKernelGGL(combine_k,   dim3(32),     dim3(512), 0, stream, agg, out);
}

// Round 17
// 35.031 us; speedup vs baseline: 1.1936x; 1.1936x over previous
//
#include <hip/hip_runtime.h>
#include <hip/hip_bf16.h>
#include <stdint.h>

// LS2T order-4 iterated sums. B=32,T=2048,F=128,m=64,C=10.
// R17 = R14 VERBATIM (session-best, deterministic, 35.07us):
//   prep_w_k: W fp32 -> bf16 MFMA B-fragments in ws.
//   ls2t_main_k: per-64t-segment fused GEMM+scan. DMA'd W (global_load_lds)
//     into dedicated 32KB double-buffer, 16KB swizzled X tile, 10-phase
//     counted-vmcnt(4) pipeline (never drained mid-loop), A-frags hoisted
//     to registers once, in-register iterated-sum scan + shfl_xor butterfly
//     merge (Chen composition over ordered monoid).
//   combine_k: 512-thr per-batch fold of 32 segment aggregates + LDS tree.
// Sync-structure variants (xs overlay R12/R13, fused election R16) all
// raced non-deterministically -> abandoned; this is the proven anchor.

typedef __attribute__((ext_vector_type(8))) short short8;
typedef __attribute__((ext_vector_type(4))) float f32x4;

#define T_ 2048
#define F_ 128
#define M_ 64
#define NTILE 40
#define SEGS 32

#define VMCNT(n) asm volatile("s_waitcnt vmcnt(" #n ")" ::: "memory")

__device__ __forceinline__ unsigned short f2bf(float x){
  unsigned int u = __float_as_uint(x);
  u += 0x7FFFu + ((u>>16)&1u);       // RNE
  return (unsigned short)(u>>16);
}

__device__ __forceinline__ void gl_lds16(const char* g, char* s){
  __builtin_amdgcn_global_load_lds(
    (const __attribute__((address_space(1))) unsigned int*)g,
    (__attribute__((address_space(3))) unsigned int*)s, 16, 0, 0);
}

// ---- Kernel 1: W fp32 -> bf16 MFMA B-fragments ----
__global__ __launch_bounds__(256) void prep_w_k(const float* __restrict__ Wk,
                                                uint4* __restrict__ wsw){
  int g = blockIdx.x*256 + threadIdx.x;
  if (g >= NTILE*4*64) return;
  int l  = g & 63;
  int kk = (g >> 6) & 3;
  int n  = g >> 8;
  int cm = n*16 + (l & 15);
  int c  = cm >> 6, mm = cm & 63;
  int kb = kk*32 + (l>>4)*8;
  unsigned short v[8];
  #pragma unroll
  for (int j=0;j<8;++j) v[j] = f2bf(Wk[((c*F_) + kb + j)*M_ + mm]);
  uint4 o;
  o.x = (unsigned)v[0] | ((unsigned)v[1]<<16);
  o.y = (unsigned)v[2] | ((unsigned)v[3]<<16);
  o.z = (unsigned)v[4] | ((unsigned)v[5]<<16);
  o.w = (unsigned)v[6] | ((unsigned)v[7]<<16);
  wsw[g] = o;
}

__device__ __forceinline__ float sx(float v, int mk){ return __shfl_xor(v, mk, 64); }

// ---- Kernel 2: fused GEMM + in-register scan, 10-phase W pipeline ----
// grid (seg=32, b=32), 256 thr = 4 waves, wave = nt (16-m slice), 64 t/wave.
__global__ __launch_bounds__(256) void ls2t_main_k(const float* __restrict__ X,
                                                   const float* __restrict__ bias,
                                                   const char* __restrict__ wsrc,
                                                   float* __restrict__ agg){
  const int seg = blockIdx.x;
  const int b   = blockIdx.y;
  const int tid = threadIdx.x;
  const int nt  = tid >> 6;
  const int l   = tid & 63;
  const int lr  = l & 15, lg = l >> 4;
  const int t0  = seg*64;
  const int mcol = nt*16 + lr;

  __shared__ __align__(16) char xs[16384];     // X tile bf16, swizzled
  __shared__ __align__(16) char wbuf[32768];   // 2 x 16KB W comp buffers

  // Stage comp c's fragments for THIS wave's quarter into buf (DMA, no VGPR).
  auto stageC = [&](int c, int buf){
    const char* s = wsrc + c*16384 + nt*4096 + l*16;
    char* d = wbuf + buf*16384 + nt*4096 + l*16;
    #pragma unroll
    for (int i=0;i<4;++i) gl_lds16(s + i*1024, d + i*1024);
  };

  // Prefetch c0,c1 (drained by the syncthreads below).
  stageC(0,0); stageC(1,1);

  // Hoisted bias.
  float bz[10];
  #pragma unroll
  for (int c=0;c<10;++c) bz[c] = bias[c*M_ + mcol];

  // Stage X: addr = t*256 + (fblk ^ ((t>>2)&7))*16, fblk = f/8 (16B units)
  #pragma unroll
  for (int p=0;p<2;++p){
    int t  = tid & 63;
    int fp = (tid >> 6) + p*4;            // 0..7
    const float* src = X + ((size_t)b*T_ + t0 + t)*F_ + fp*16;
    float4 v0 = *reinterpret_cast<const float4*>(src);
    float4 v1 = *reinterpret_cast<const float4*>(src+4);
    float4 v2 = *reinterpret_cast<const float4*>(src+8);
    float4 v3 = *reinterpret_cast<const float4*>(src+12);
    uint4 q0, q1;
    q0.x = (unsigned)f2bf(v0.x) | ((unsigned)f2bf(v0.y)<<16);
    q0.y = (unsigned)f2bf(v0.z) | ((unsigned)f2bf(v0.w)<<16);
    q0.z = (unsigned)f2bf(v1.x) | ((unsigned)f2bf(v1.y)<<16);
    q0.w = (unsigned)f2bf(v1.z) | ((unsigned)f2bf(v1.w)<<16);
    q1.x = (unsigned)f2bf(v2.x) | ((unsigned)f2bf(v2.y)<<16);
    q1.y = (unsigned)f2bf(v2.z) | ((unsigned)f2bf(v2.w)<<16);
    q1.z = (unsigned)f2bf(v3.x) | ((unsigned)f2bf(v3.y)<<16);
    q1.w = (unsigned)f2bf(v3.z) | ((unsigned)f2bf(v3.w)<<16);
    int sw = (t>>2)&7;
    *reinterpret_cast<uint4*>(xs + t*256 + ((fp*2  ) ^ sw)*16) = q0;
    *reinterpret_cast<uint4*>(xs + t*256 + ((fp*2+1) ^ sw)*16) = q1;
  }
  __syncthreads();   // xs visible to all; drains c0/c1 DMA too.

  // Hoist A-fragments into registers ONCE (constant across all 10 phases).
  short8 af[4][4];
  #pragma unroll
  for (int s=0;s<4;++s)
    #pragma unroll
    for (int kk=0;kk<4;++kk)
      af[s][kk] = *reinterpret_cast<const short8*>(
          xs + (lr*4+s)*256 + (((kk*4+lg) ^ (lr&7)))*16);

  // MFMA c from buf into A[4] using register-resident af.
  auto computeC = [&](f32x4 (&A)[4], int buf){
    const char* wb = wbuf + buf*16384 + nt*4096;
    #pragma unroll
    for (int s=0;s<4;++s) A[s] = (f32x4){0.f,0.f,0.f,0.f};
    #pragma unroll
    for (int kk=0;kk<4;++kk){
      short8 wf = *reinterpret_cast<const short8*>(wb + kk*1024 + l*16);
      #pragma unroll
      for (int s=0;s<4;++s)
        A[s] = __builtin_amdgcn_mfma_f32_16x16x32_bf16(af[s][kk], wf, A[s], 0,0,0);
    }
  };

  float* ob = agg + (((size_t)b*SEGS + seg)*20)*64 + mcol;
  f32x4 A0[4], A1[4], A2[4], A3[4];

  // ---- P0: c0 (b0) -> level 1 scan; stage c2->b0 ----
  computeC(A0,0);
  stageC(2,0);
  {
    float S0 = 0.f;
    #pragma unroll
    for (int j=0;j<4;++j)
      #pragma unroll
      for (int s=0;s<4;++s) S0 += A0[s][j] + bz[0];
    #pragma unroll
    for (int st=0; st<2; ++st) S0 += sx(S0, 16<<st);
    if (lg==0) ob[0*64] = S0;
  }
  // ---- P1: c1 (b1) -> A0; stage c3->b1 ----
  computeC(A0,1);
  stageC(3,1);
  // ---- P2: c2 (b0) -> A1; stage c4->b0; level 2 scan ----
  VMCNT(4);
  computeC(A1,0);
  stageC(4,0);
  {
    float S1=0.f,S2=0.f,I21=0.f;
    #pragma unroll
    for (int j=0;j<4;++j)
      #pragma unroll
      for (int s=0;s<4;++s){
        float a1 = A0[s][j] + bz[1];
        float a2 = A1[s][j] + bz[2];
        I21 += a2*S1; S1 += a1; S2 += a2;
      }
    #pragma unroll
    for (int st=0; st<2; ++st){
      int mk = 16<<st; bool up = (l & mk)!=0;
      float o1=sx(S1,mk), o2=sx(S2,mk), oI=sx(I21,mk);
      float B1=up?o1:S1, B2=up?o2:S2, BI=up?oI:I21;
      float C1=up?S1:o1, C2=up?S2:o2, CI=up?I21:oI;
      S1=B1+C1; S2=B2+C2; I21=BI+CI + B1*C2;
    }
    if (lg==0) ob[1*64]=S1; else if (lg==1) ob[2*64]=S2; else if (lg==2) ob[10*64]=I21;
  }
  // ---- P3: c3 (b1) -> A0; stage c5->b1 ----
  VMCNT(4);
  computeC(A0,1);
  stageC(5,1);
  // ---- P4: c4 (b0) -> A1; stage c6->b0 ----
  VMCNT(4);
  computeC(A1,0);
  stageC(6,0);
  // ---- P5: c5 (b1) -> A2; stage c7->b1; level 3 scan ----
  VMCNT(4);
  computeC(A2,1);
  stageC(7,1);
  {
    float S3=0.f,S4=0.f,S5=0.f,I43=0.f,I54=0.f,I543=0.f;
    #pragma unroll
    for (int j=0;j<4;++j)
      #pragma unroll
      for (int s=0;s<4;++s){
        float a3 = A0[s][j] + bz[3];
        float a4 = A1[s][j] + bz[4];
        float a5 = A2[s][j] + bz[5];
        I543 += a5*I43; I54 += a5*S4; I43 += a4*S3;
        S3 += a3; S4 += a4; S5 += a5;
      }
    #pragma unroll
    for (int st=0; st<2; ++st){
      int mk = 16<<st; bool up = (l & mk)!=0;
      float o3=sx(S3,mk), o4=sx(S4,mk), o5=sx(S5,mk);
      float oA=sx(I43,mk), oB=sx(I54,mk), oC=sx(I543,mk);
      float B3=up?o3:S3, B4=up?o4:S4, B5=up?o5:S5;
      float BA=up?oA:I43, BB=up?oB:I54, BC_=up?oC:I543;
      float C3=up?S3:o3, C4=up?S4:o4, C5=up?S5:o5;
      float CA=up?I43:oA, CB=up?I54:oB, CC=up?I543:oC;
      float n43 = BA+CA + B3*C4;
      float n54 = BB+CB + B4*C5;
      float n543= BC_+CC + BA*C5 + B3*CB;
      S3=B3+C3; S4=B4+C4; S5=B5+C5; I43=n43; I54=n54; I543=n543;
    }
    if      (lg==0){ ob[3*64]=S3;  ob[11*64]=I43; }
    else if (lg==1){ ob[4*64]=S4;  ob[12*64]=I54; }
    else if (lg==2){ ob[5*64]=S5;  ob[13*64]=I543; }
  }
  // ---- P6: c6 (b0) -> A0; stage c8->b0 ----
  VMCNT(4);
  computeC(A0,0);
  stageC(8,0);
  // ---- P7: c7 (b1) -> A1; stage c9->b1 ----
  VMCNT(4);
  computeC(A1,1);
  stageC(9,1);
  // ---- P8: c8 (b0) -> A2 ----
  VMCNT(4);
  computeC(A2,0);
  // ---- P9: c9 (b1) -> A3; level 4 scan ----
  VMCNT(0);
  computeC(A3,1);
  {
    float S6=0.f,S7=0.f,S8=0.f,S9=0.f;
    float I76=0.f,I87=0.f,I98=0.f,I876=0.f,I987=0.f,I9876=0.f;
    #pragma unroll
    for (int j=0;j<4;++j)
      #pragma unroll
      for (int s=0;s<4;++s){
        float a6 = A0[s][j] + bz[6];
        float a7 = A1[s][j] + bz[7];
        float a8 = A2[s][j] + bz[8];
        float a9 = A3[s][j] + bz[9];
        I9876 += a9*I876; I987 += a9*I87; I98 += a9*S8;
        I876  += a8*I76;  I87  += a8*S7;
        I76   += a7*S6;
        S6 += a6; S7 += a7; S8 += a8; S9 += a9;
      }
    #pragma unroll
    for (int st=0; st<2; ++st){
      int mk = 16<<st; bool up = (l & mk)!=0;
      float o6=sx(S6,mk), o7=sx(S7,mk), o8=sx(S8,mk), o9=sx(S9,mk);
      float oA=sx(I76,mk), oB=sx(I87,mk), oC=sx(I98,mk);
      float oD=sx(I876,mk), oE=sx(I987,mk), oF=sx(I9876,mk);
      float B6=up?o6:S6, B7=up?o7:S7, B8=up?o8:S8, B9=up?o9:S9;
      float BA=up?oA:I76, BB=up?oB:I87, BC_=up?oC:I98;
      float BD=up?oD:I876, BE=up?oE:I987, BF=up?oF:I9876;
      float C6=up?S6:o6, C7=up?S7:o7, C8=up?S8:o8, C9=up?S9:o9;
      float CA=up?I76:oA, CB=up?I87:oB, CC=up?I98:oC;
      float CD=up?I876:oD, CE=up?I987:oE, CF=up?I9876:oF;
      float n76  = BA+CA + B6*C7;
      float n87  = BB+CB + B7*C8;
      float n98  = BC_+CC + B8*C9;
      float n876 = BD+CD + BA*C8 + B6*CB;
      float n987 = BE+CE + BB*C9 + B7*CC;
      float n9876= BF+CF + BD*C9 + BA*CC + B6*CE;
      S6=B6+C6; S7=B7+C7; S8=B8+C8; S9=B9+C9;
      I76=n76; I87=n87; I98=n98; I876=n876; I987=n987; I9876=n9876;
    }
    if      (lg==0){ ob[6*64]=S6; ob[14*64]=I76; ob[18*64]=I987; }
    else if (lg==1){ ob[7*64]=S7; ob[15*64]=I87; ob[19*64]=I9876; }
    else if (lg==2){ ob[8*64]=S8; ob[16*64]=I98; }
    else           { ob[9*64]=S9; ob[17*64]=I876; }
  }
}

// state layout: [0..9]=S0..S9, [10]=I21,[11]=I43,[12]=I54,[13]=I543,
// [14]=I76,[15]=I87,[16]=I98,[17]=I876,[18]=I987,[19]=I9876
__device__ __forceinline__ void compose(float* A, const float* Bv){
  float n10 = A[10]+Bv[10] + A[1]*Bv[2];
  float n11 = A[11]+Bv[11] + A[3]*Bv[4];
  float n12 = A[12]+Bv[12] + A[4]*Bv[5];
  float n13 = A[13]+Bv[13] + A[11]*Bv[5] + A[3]*Bv[12];
  float n14 = A[14]+Bv[14] + A[6]*Bv[7];
  float n15 = A[15]+Bv[15] + A[7]*Bv[8];
  float n16 = A[16]+Bv[16] + A[8]*Bv[9];
  float n17 = A[17]+Bv[17] + A[14]*Bv[8] + A[6]*Bv[15];
  float n18 = A[18]+Bv[18] + A[15]*Bv[9] + A[7]*Bv[16];
  float n19 = A[19]+Bv[19] + A[17]*Bv[9] + A[14]*Bv[16] + A[6]*Bv[18];
  #pragma unroll
  for (int c=0;c<10;++c) A[c] += Bv[c];
  A[10]=n10; A[11]=n11; A[12]=n12; A[13]=n13; A[14]=n14;
  A[15]=n15; A[16]=n16; A[17]=n17; A[18]=n18; A[19]=n19;
}

// ---- Kernel 3: fold 32 segments per (b,m); 8-way parallel + LDS tree ----
__global__ __launch_bounds__(512) void combine_k(const float* __restrict__ agg,
                                                 float* __restrict__ out){
  int b  = blockIdx.x;            // 32 blocks
  int m  = threadIdx.x & 63;
  int sg = threadIdx.x >> 6;      // 0..7, folds segs [sg*4, sg*4+4)
  const float* base = agg + ((size_t)b*SEGS*20)*64 + m;
  float st[20];
  #pragma unroll
  for (int i=0;i<20;++i) st[i]=0.f;
  for (int s=sg*4; s<sg*4+4; ++s){
    const float* a = base + (size_t)s*20*64;
    float Bv[20];
    #pragma unroll
    for (int i=0;i<20;++i) Bv[i] = a[i*64];
    compose(st, Bv);
  }
  __shared__ float buf[8][20][64];   // 40KB
  #pragma unroll
  for (int i=0;i<20;++i) buf[sg][i][m] = st[i];
  __syncthreads();
  if (sg==0){
    #pragma unroll
    for (int g=1; g<8; ++g){
      float Bv[20];
      #pragma unroll
      for (int i=0;i<20;++i) Bv[i] = buf[g][i][m];
      compose(st, Bv);
    }
    out[(b*4+0)*64+m] = st[0];    // y1 = S0 total
    out[(b*4+1)*64+m] = st[10];   // y2 = I21 total
    out[(b*4+2)*64+m] = st[13];   // y3 = I543 total
    out[(b*4+3)*64+m] = st[19];   // y4 = I9876 total
  }
}

extern "C" void kernel_launch(void* const* d_in, const int* in_sizes, int n_in,
                              void* d_out, int out_size, void* d_ws, size_t ws_size,
                              hipStream_t stream){
  const float* X    = (const float*)d_in[0];   // [32,2048,128]
  const float* Wk   = (const float*)d_in[1];   // [10,128,64]
  const float* bias = (const float*)d_in[2];   // [10,64]
  float* out = (float*)d_out;                  // [32,4,64]

  uint4* wsw = (uint4*)d_ws;                                 // 160 KB W frags
  float* agg = (float*)((char*)d_ws + (1u<<20));             // 5.25 MB aggregates

  hipLaunchKernelGGL(prep_w_k,    dim3(40),     dim3(256), 0, stream, Wk, wsw);
  hipLaunchKernelGGL(ls2t_main_k, dim3(32,32),  dim3(256), 0, stream,
                     X, bias, (const char*)d_ws, agg);
  hipLaunchKernelGGL(combine_k,   dim3(32),     dim3(512), 0, stream, agg, out);
}

// Round 18
// 32.952 us; speedup vs baseline: 1.2689x; 1.0631x over previous
//
#include <hip/hip_runtime.h>
#include <hip/hip_bf16.h>
#include <stdint.h>

// LS2T order-4 iterated sums. B=32,T=2048,F=128,m=64,C=10.
// R18 = R14 pipeline VERBATIM, with the X tile halved (16->8KB) by staging
// X in two 32-t halves into the SAME 8KB buffer, each behind a full
// __syncthreads() (drains vmcnt+lgkmcnt; no counted DMA ever targets xs;
// both W prefetches remain before the final barrier exactly as R14).
// Lane lr only needs rows lr*4+s: half0 serves lr<8, half1 serves lr>=8;
// local-row addressing is identical for both halves.
// LDS 48->40KB -> 4 blocks/CU (4x40KB = 160KB exactly): 1024-block grid is
// ONE co-residency batch (R14 ran 768+256 with a quarter-occupancy tail).

typedef __attribute__((ext_vector_type(8))) short short8;
typedef __attribute__((ext_vector_type(4))) float f32x4;

#define T_ 2048
#define F_ 128
#define M_ 64
#define NTILE 40
#define SEGS 32

#define VMCNT(n) asm volatile("s_waitcnt vmcnt(" #n ")" ::: "memory")

__device__ __forceinline__ unsigned short f2bf(float x){
  unsigned int u = __float_as_uint(x);
  u += 0x7FFFu + ((u>>16)&1u);       // RNE
  return (unsigned short)(u>>16);
}

__device__ __forceinline__ void gl_lds16(const char* g, char* s){
  __builtin_amdgcn_global_load_lds(
    (const __attribute__((address_space(1))) unsigned int*)g,
    (__attribute__((address_space(3))) unsigned int*)s, 16, 0, 0);
}

// ---- Kernel 1: W fp32 -> bf16 MFMA B-fragments ----
__global__ __launch_bounds__(256) void prep_w_k(const float* __restrict__ Wk,
                                                uint4* __restrict__ wsw){
  int g = blockIdx.x*256 + threadIdx.x;
  if (g >= NTILE*4*64) return;
  int l  = g & 63;
  int kk = (g >> 6) & 3;
  int n  = g >> 8;
  int cm = n*16 + (l & 15);
  int c  = cm >> 6, mm = cm & 63;
  int kb = kk*32 + (l>>4)*8;
  unsigned short v[8];
  #pragma unroll
  for (int j=0;j<8;++j) v[j] = f2bf(Wk[((c*F_) + kb + j)*M_ + mm]);
  uint4 o;
  o.x = (unsigned)v[0] | ((unsigned)v[1]<<16);
  o.y = (unsigned)v[2] | ((unsigned)v[3]<<16);
  o.z = (unsigned)v[4] | ((unsigned)v[5]<<16);
  o.w = (unsigned)v[6] | ((unsigned)v[7]<<16);
  wsw[g] = o;
}

__device__ __forceinline__ float sx(float v, int mk){ return __shfl_xor(v, mk, 64); }

// ---- Kernel 2: fused GEMM + in-register scan, 10-phase W pipeline ----
// grid (seg=32, b=32), 256 thr = 4 waves, wave = nt (16-m slice), 64 t/wave.
__global__ __launch_bounds__(256) void ls2t_main_k(const float* __restrict__ X,
                                                   const float* __restrict__ bias,
                                                   const char* __restrict__ wsrc,
                                                   float* __restrict__ agg){
  const int seg = blockIdx.x;
  const int b   = blockIdx.y;
  const int tid = threadIdx.x;
  const int nt  = tid >> 6;
  const int l   = tid & 63;
  const int lr  = l & 15, lg = l >> 4;
  const int t0  = seg*64;
  const int mcol = nt*16 + lr;

  __shared__ __align__(16) char xs[8192];      // X half-tile bf16, swizzled
  __shared__ __align__(16) char wbuf[32768];   // 2 x 16KB W comp buffers

  // Stage comp c's fragments for THIS wave's quarter into buf (DMA, no VGPR).
  auto stageC = [&](int c, int buf){
    const char* s = wsrc + c*16384 + nt*4096 + l*16;
    char* d = wbuf + buf*16384 + nt*4096 + l*16;
    #pragma unroll
    for (int i=0;i<4;++i) gl_lds16(s + i*1024, d + i*1024);
  };

  // Prefetch c0,c1 into wbuf (never aliased; drained by the barriers below).
  stageC(0,0); stageC(1,1);

  // Hoisted bias.
  float bz[10];
  #pragma unroll
  for (int c=0;c<10;++c) bz[c] = bias[c*M_ + mcol];

  // Stage one 32-t half of X into xs: thread (t=tid&31, fp=tid>>5) converts
  // 16 floats -> 2 x 16B bf16 blocks at row t (local), swizzle (t>>2)&7.
  auto stageX = [&](int half){
    int t  = tid & 31;
    int fp = tid >> 5;                  // 0..7
    const float* src = X + ((size_t)b*T_ + t0 + half*32 + t)*F_ + fp*16;
    float4 v0 = *reinterpret_cast<const float4*>(src);
    float4 v1 = *reinterpret_cast<const float4*>(src+4);
    float4 v2 = *reinterpret_cast<const float4*>(src+8);
    float4 v3 = *reinterpret_cast<const float4*>(src+12);
    uint4 q0, q1;
    q0.x = (unsigned)f2bf(v0.x) | ((unsigned)f2bf(v0.y)<<16);
    q0.y = (unsigned)f2bf(v0.z) | ((unsigned)f2bf(v0.w)<<16);
    q0.z = (unsigned)f2bf(v1.x) | ((unsigned)f2bf(v1.y)<<16);
    q0.w = (unsigned)f2bf(v1.z) | ((unsigned)f2bf(v1.w)<<16);
    q1.x = (unsigned)f2bf(v2.x) | ((unsigned)f2bf(v2.y)<<16);
    q1.y = (unsigned)f2bf(v2.z) | ((unsigned)f2bf(v2.w)<<16);
    q1.z = (unsigned)f2bf(v3.x) | ((unsigned)f2bf(v3.y)<<16);
    q1.w = (unsigned)f2bf(v3.z) | ((unsigned)f2bf(v3.w)<<16);
    int sw = (t>>2)&7;
    *reinterpret_cast<uint4*>(xs + t*256 + ((fp*2  ) ^ sw)*16) = q0;
    *reinterpret_cast<uint4*>(xs + t*256 + ((fp*2+1) ^ sw)*16) = q1;
  };
  // af-hoist from the current half for this lane (local rows (lr&7)*4+s).
  short8 af[4][4];
  auto hoistAf = [&](){
    #pragma unroll
    for (int s=0;s<4;++s)
      #pragma unroll
      for (int kk=0;kk<4;++kk)
        af[s][kk] = *reinterpret_cast<const short8*>(
            xs + ((lr&7)*4+s)*256 + (((kk*4+lg) ^ (lr&7)))*16);
  };

  stageX(0);
  __syncthreads();                 // half0 visible; drains X loads + W DMA
  if (lr < 8) hoistAf();           // lanes lr<8 own rows 0..31
  __syncthreads();                 // all half0 reads complete (lgkm drained)
  stageX(1);
  __syncthreads();                 // half1 visible; vmcnt fully drained ->
                                   // counted pipeline anchor == R14's barrier
  if (lr >= 8) hoistAf();          // lanes lr>=8 own rows 32..63

  // MFMA c from buf into A[4] using register-resident af.
  auto computeC = [&](f32x4 (&A)[4], int buf){
    const char* wb = wbuf + buf*16384 + nt*4096;
    #pragma unroll
    for (int s=0;s<4;++s) A[s] = (f32x4){0.f,0.f,0.f,0.f};
    #pragma unroll
    for (int kk=0;kk<4;++kk){
      short8 wf = *reinterpret_cast<const short8*>(wb + kk*1024 + l*16);
      #pragma unroll
      for (int s=0;s<4;++s)
        A[s] = __builtin_amdgcn_mfma_f32_16x16x32_bf16(af[s][kk], wf, A[s], 0,0,0);
    }
  };

  float* ob = agg + (((size_t)b*SEGS + seg)*20)*64 + mcol;
  f32x4 A0[4], A1[4], A2[4], A3[4];

  // ---- P0: c0 (b0) -> level 1 scan; stage c2->b0 ----
  computeC(A0,0);
  stageC(2,0);
  {
    float S0 = 0.f;
    #pragma unroll
    for (int j=0;j<4;++j)
      #pragma unroll
      for (int s=0;s<4;++s) S0 += A0[s][j] + bz[0];
    #pragma unroll
    for (int st=0; st<2; ++st) S0 += sx(S0, 16<<st);
    if (lg==0) ob[0*64] = S0;
  }
  // ---- P1: c1 (b1) -> A0; stage c3->b1 ----
  computeC(A0,1);
  stageC(3,1);
  // ---- P2: c2 (b0) -> A1; stage c4->b0; level 2 scan ----
  VMCNT(4);
  computeC(A1,0);
  stageC(4,0);
  {
    float S1=0.f,S2=0.f,I21=0.f;
    #pragma unroll
    for (int j=0;j<4;++j)
      #pragma unroll
      for (int s=0;s<4;++s){
        float a1 = A0[s][j] + bz[1];
        float a2 = A1[s][j] + bz[2];
        I21 += a2*S1; S1 += a1; S2 += a2;
      }
    #pragma unroll
    for (int st=0; st<2; ++st){
      int mk = 16<<st; bool up = (l & mk)!=0;
      float o1=sx(S1,mk), o2=sx(S2,mk), oI=sx(I21,mk);
      float B1=up?o1:S1, B2=up?o2:S2, BI=up?oI:I21;
      float C1=up?S1:o1, C2=up?S2:o2, CI=up?I21:oI;
      S1=B1+C1; S2=B2+C2; I21=BI+CI + B1*C2;
    }
    if (lg==0) ob[1*64]=S1; else if (lg==1) ob[2*64]=S2; else if (lg==2) ob[10*64]=I21;
  }
  // ---- P3: c3 (b1) -> A0; stage c5->b1 ----
  VMCNT(4);
  computeC(A0,1);
  stageC(5,1);
  // ---- P4: c4 (b0) -> A1; stage c6->b0 ----
  VMCNT(4);
  computeC(A1,0);
  stageC(6,0);
  // ---- P5: c5 (b1) -> A2; stage c7->b1; level 3 scan ----
  VMCNT(4);
  computeC(A2,1);
  stageC(7,1);
  {
    float S3=0.f,S4=0.f,S5=0.f,I43=0.f,I54=0.f,I543=0.f;
    #pragma unroll
    for (int j=0;j<4;++j)
      #pragma unroll
      for (int s=0;s<4;++s){
        float a3 = A0[s][j] + bz[3];
        float a4 = A1[s][j] + bz[4];
        float a5 = A2[s][j] + bz[5];
        I543 += a5*I43; I54 += a5*S4; I43 += a4*S3;
        S3 += a3; S4 += a4; S5 += a5;
      }
    #pragma unroll
    for (int st=0; st<2; ++st){
      int mk = 16<<st; bool up = (l & mk)!=0;
      float o3=sx(S3,mk), o4=sx(S4,mk), o5=sx(S5,mk);
      float oA=sx(I43,mk), oB=sx(I54,mk), oC=sx(I543,mk);
      float B3=up?o3:S3, B4=up?o4:S4, B5=up?o5:S5;
      float BA=up?oA:I43, BB=up?oB:I54, BC_=up?oC:I543;
      float C3=up?S3:o3, C4=up?S4:o4, C5=up?S5:o5;
      float CA=up?I43:oA, CB=up?I54:oB, CC=up?I543:oC;
      float n43 = BA+CA + B3*C4;
      float n54 = BB+CB + B4*C5;
      float n543= BC_+CC + BA*C5 + B3*CB;
      S3=B3+C3; S4=B4+C4; S5=B5+C5; I43=n43; I54=n54; I543=n543;
    }
    if      (lg==0){ ob[3*64]=S3;  ob[11*64]=I43; }
    else if (lg==1){ ob[4*64]=S4;  ob[12*64]=I54; }
    else if (lg==2){ ob[5*64]=S5;  ob[13*64]=I543; }
  }
  // ---- P6: c6 (b0) -> A0; stage c8->b0 ----
  VMCNT(4);
  computeC(A0,0);
  stageC(8,0);
  // ---- P7: c7 (b1) -> A1; stage c9->b1 ----
  VMCNT(4);
  computeC(A1,1);
  stageC(9,1);
  // ---- P8: c8 (b0) -> A2 ----
  VMCNT(4);
  computeC(A2,0);
  // ---- P9: c9 (b1) -> A3; level 4 scan ----
  VMCNT(0);
  computeC(A3,1);
  {
    float S6=0.f,S7=0.f,S8=0.f,S9=0.f;
    float I76=0.f,I87=0.f,I98=0.f,I876=0.f,I987=0.f,I9876=0.f;
    #pragma unroll
    for (int j=0;j<4;++j)
      #pragma unroll
      for (int s=0;s<4;++s){
        float a6 = A0[s][j] + bz[6];
        float a7 = A1[s][j] + bz[7];
        float a8 = A2[s][j] + bz[8];
        float a9 = A3[s][j] + bz[9];
        I9876 += a9*I876; I987 += a9*I87; I98 += a9*S8;
        I876  += a8*I76;  I87  += a8*S7;
        I76   += a7*S6;
        S6 += a6; S7 += a7; S8 += a8; S9 += a9;
      }
    #pragma unroll
    for (int st=0; st<2; ++st){
      int mk = 16<<st; bool up = (l & mk)!=0;
      float o6=sx(S6,mk), o7=sx(S7,mk), o8=sx(S8,mk), o9=sx(S9,mk);
      float oA=sx(I76,mk), oB=sx(I87,mk), oC=sx(I98,mk);
      float oD=sx(I876,mk), oE=sx(I987,mk), oF=sx(I9876,mk);
      float B6=up?o6:S6, B7=up?o7:S7, B8=up?o8:S8, B9=up?o9:S9;
      float BA=up?oA:I76, BB=up?oB:I87, BC_=up?oC:I98;
      float BD=up?oD:I876, BE=up?oE:I987, BF=up?oF:I9876;
      float C6=up?S6:o6, C7=up?S7:o7, C8=up?S8:o8, C9=up?S9:o9;
      float CA=up?I76:oA, CB=up?I87:oB, CC=up?I98:oC;
      float CD=up?I876:oD, CE=up?I987:oE, CF=up?I9876:oF;
      float n76  = BA+CA + B6*C7;
      float n87  = BB+CB + B7*C8;
      float n98  = BC_+CC + B8*C9;
      float n876 = BD+CD + BA*C8 + B6*CB;
      float n987 = BE+CE + BB*C9 + B7*CC;
      float n9876= BF+CF + BD*C9 + BA*CC + B6*CE;
      S6=B6+C6; S7=B7+C7; S8=B8+C8; S9=B9+C9;
      I76=n76; I87=n87; I98=n98; I876=n876; I987=n987; I9876=n9876;
    }
    if      (lg==0){ ob[6*64]=S6; ob[14*64]=I76; ob[18*64]=I987; }
    else if (lg==1){ ob[7*64]=S7; ob[15*64]=I87; ob[19*64]=I9876; }
    else if (lg==2){ ob[8*64]=S8; ob[16*64]=I98; }
    else           { ob[9*64]=S9; ob[17*64]=I876; }
  }
}

// state layout: [0..9]=S0..S9, [10]=I21,[11]=I43,[12]=I54,[13]=I543,
// [14]=I76,[15]=I87,[16]=I98,[17]=I876,[18]=I987,[19]=I9876
__device__ __forceinline__ void compose(float* A, const float* Bv){
  float n10 = A[10]+Bv[10] + A[1]*Bv[2];
  float n11 = A[11]+Bv[11] + A[3]*Bv[4];
  float n12 = A[12]+Bv[12] + A[4]*Bv[5];
  float n13 = A[13]+Bv[13] + A[11]*Bv[5] + A[3]*Bv[12];
  float n14 = A[14]+Bv[14] + A[6]*Bv[7];
  float n15 = A[15]+Bv[15] + A[7]*Bv[8];
  float n16 = A[16]+Bv[16] + A[8]*Bv[9];
  float n17 = A[17]+Bv[17] + A[14]*Bv[8] + A[6]*Bv[15];
  float n18 = A[18]+Bv[18] + A[15]*Bv[9] + A[7]*Bv[16];
  float n19 = A[19]+Bv[19] + A[17]*Bv[9] + A[14]*Bv[16] + A[6]*Bv[18];
  #pragma unroll
  for (int c=0;c<10;++c) A[c] += Bv[c];
  A[10]=n10; A[11]=n11; A[12]=n12; A[13]=n13; A[14]=n14;
  A[15]=n15; A[16]=n16; A[17]=n17; A[18]=n18; A[19]=n19;
}

// ---- Kernel 3: fold 32 segments per (b,m); 8-way parallel + LDS tree ----
__global__ __launch_bounds__(512) void combine_k(const float* __restrict__ agg,
                                                 float* __restrict__ out){
  int b  = blockIdx.x;            // 32 blocks
  int m  = threadIdx.x & 63;
  int sg = threadIdx.x >> 6;      // 0..7, folds segs [sg*4, sg*4+4)
  const float* base = agg + ((size_t)b*SEGS*20)*64 + m;
  float st[20];
  #pragma unroll
  for (int i=0;i<20;++i) st[i]=0.f;
  for (int s=sg*4; s<sg*4+4; ++s){
    const float* a = base + (size_t)s*20*64;
    float Bv[20];
    #pragma unroll
    for (int i=0;i<20;++i) Bv[i] = a[i*64];
    compose(st, Bv);
  }
  __shared__ float buf[8][20][64];   // 40KB
  #pragma unroll
  for (int i=0;i<20;++i) buf[sg][i][m] = st[i];
  __syncthreads();
  if (sg==0){
    #pragma unroll
    for (int g=1; g<8; ++g){
      float Bv[20];
      #pragma unroll
      for (int i=0;i<20;++i) Bv[i] = buf[g][i][m];
      compose(st, Bv);
    }
    out[(b*4+0)*64+m] = st[0];    // y1 = S0 total
    out[(b*4+1)*64+m] = st[10];   // y2 = I21 total
    out[(b*4+2)*64+m] = st[13];   // y3 = I543 total
    out[(b*4+3)*64+m] = st[19];   // y4 = I9876 total
  }
}

extern "C" void kernel_launch(void* const* d_in, const int* in_sizes, int n_in,
                              void* d_out, int out_size, void* d_ws, size_t ws_size,
                              hipStream_t stream){
  const float* X    = (const float*)d_in[0];   // [32,2048,128]
  const float* Wk   = (const float*)d_in[1];   // [10,128,64]
  const float* bias = (const float*)d_in[2];   // [10,64]
  float* out = (float*)d_out;                  // [32,4,64]

  uint4* wsw = (uint4*)d_ws;                                 // 160 KB W frags
  float* agg = (float*)((char*)d_ws + (1u<<20));             // 5.25 MB aggregates

  hipLaunchKernelGGL(prep_w_k,    dim3(40),     dim3(256), 0, stream, Wk, wsw);
  hipLaunchKernelGGL(ls2t_main_k, dim3(32,32),  dim3(256), 0, stream,
                     X, bias, (const char*)d_ws, agg);
  hipLaunchKernelGGL(combine_k,   dim3(32),     dim3(512), 0, stream, agg, out);
}